// Round 2
// baseline (100.928 us; speedup 1.0000x reference)
//
#include <hip/hip_runtime.h>

typedef unsigned short u16;
typedef unsigned int u32;
typedef __attribute__((ext_vector_type(8))) short short8;
typedef __attribute__((ext_vector_type(4))) float f32x4;
typedef __attribute__((ext_vector_type(4))) unsigned short ushort4v;
typedef __attribute__((ext_vector_type(4))) float float4v;

// ---------- helpers ----------
__device__ __forceinline__ float bf2f(u16 u) {
    return __uint_as_float(((u32)u) << 16);
}
__device__ __forceinline__ u16 f2bf(float f) {
    u32 u = __float_as_uint(f);
    u += 0x7FFF + ((u >> 16) & 1);   // RNE
    return (u16)(u >> 16);
}

// async global->LDS, 16B per lane; dst must be wave-uniform (HW adds lane*16)
__device__ __forceinline__ void stage16(const u16* g, u16* l) {
    __builtin_amdgcn_global_load_lds(
        (const __attribute__((address_space(1))) unsigned int*)g,
        (__attribute__((address_space(3))) unsigned int*)l, 16, 0, 0);
}

// ---------- K0: fp32 -> bf16 convert ----------
__global__ __launch_bounds__(256) void cvt_bf16(const float* __restrict__ in,
                                                u16* __restrict__ out, int n4) {
    int i = blockIdx.x * 256 + threadIdx.x;
    int stride = gridDim.x * 256;
    for (; i < n4; i += stride) {
        float4v v = ((const float4v*)in)[i];
        ushort4v r;
        r[0] = f2bf(v[0]); r[1] = f2bf(v[1]); r[2] = f2bf(v[2]); r[3] = f2bf(v[3]);
        ((ushort4v*)out)[i] = r;
    }
}

// ---------- shared GEMM core: 128x128 tile, K=512, BK=32, global_load_lds staging ----------
// Ag/Bg point at the tile's first row; both are K-major with row stride 512.
__device__ __forceinline__ void gemm_core(const u16* __restrict__ Ag,
                                          const u16* __restrict__ Bg,
                                          u16* As, u16* Bs, int t,
                                          f32x4 acc[4][4]) {
    const int wv = t >> 6, l = t & 63;
    const int lr = l & 15, lk = (l >> 4) * 8;
    const int wm = (wv >> 1) * 64, wn = (wv & 1) * 64;
    const int srow = l >> 2, scol = (l & 3) * 8;   // lane's slot within a 16-row group

    u16* Ad0 = As + (wv * 32) * 32;
    u16* Ad1 = As + (wv * 32 + 16) * 32;
    u16* Bd0 = Bs + (wv * 32) * 32;
    u16* Bd1 = Bs + (wv * 32 + 16) * 32;
    const u16* As0 = Ag + (size_t)(wv * 32 + srow) * 512 + scol;
    const u16* As1 = Ag + (size_t)(wv * 32 + 16 + srow) * 512 + scol;
    const u16* Bs0 = Bg + (size_t)(wv * 32 + srow) * 512 + scol;
    const u16* Bs1 = Bg + (size_t)(wv * 32 + 16 + srow) * 512 + scol;

    for (int k0 = 0; k0 < 512; k0 += 32) {
        stage16(As0 + k0, Ad0);
        stage16(As1 + k0, Ad1);
        stage16(Bs0 + k0, Bd0);
        stage16(Bs1 + k0, Bd1);
        __syncthreads();   // drains vmcnt(0) -> staging visible
        short8 af[4], bfr[4];
#pragma unroll
        for (int mi = 0; mi < 4; ++mi)
            af[mi] = *(const short8*)(As + (wm + mi * 16 + lr) * 32 + lk);
#pragma unroll
        for (int ni = 0; ni < 4; ++ni)
            bfr[ni] = *(const short8*)(Bs + (wn + ni * 16 + lr) * 32 + lk);
#pragma unroll
        for (int mi = 0; mi < 4; ++mi)
#pragma unroll
            for (int ni = 0; ni < 4; ++ni)
                acc[mi][ni] = __builtin_amdgcn_mfma_f32_16x16x32_bf16(
                    af[mi], bfr[ni], acc[mi][ni], 0, 0, 0);
        __syncthreads();   // compute done before next stage overwrites
    }
}

// ---------- K1: kv = x @ W_kv^T  [16384 x 1024] ----------
__global__ __launch_bounds__(256) void gemm_kv(const u16* __restrict__ xb,
                                               const u16* __restrict__ wb,
                                               u16* __restrict__ kvb) {
    __shared__ u16 As[128 * 32];
    __shared__ u16 Bs[128 * 32];
    const int t = threadIdx.x;
    const int m0 = blockIdx.x * 128;
    const int n0 = blockIdx.y * 128;
    f32x4 zz = {0.f, 0.f, 0.f, 0.f};
    f32x4 acc[4][4];
    for (int i = 0; i < 4; ++i)
        for (int j = 0; j < 4; ++j) acc[i][j] = zz;

    gemm_core(xb + (size_t)m0 * 512, wb + (size_t)n0 * 512, As, Bs, t, acc);

    const int l = t & 63, wv = t >> 6;
    const int lr = l & 15;
    const int wm = (wv >> 1) * 64, wn = (wv & 1) * 64;
#pragma unroll
    for (int mi = 0; mi < 4; ++mi)
#pragma unroll
        for (int ni = 0; ni < 4; ++ni) {
            int col = n0 + wn + ni * 16 + lr;
#pragma unroll
            for (int j = 0; j < 4; ++j) {
                int row = m0 + wm + mi * 16 + (l >> 4) * 4 + j;
                kvb[(size_t)row * 1024 + col] = f2bf(acc[mi][ni][j]);
            }
        }
}

// ---------- K2a: per (b,h) partial G0 = k^T v, ksum, vsum over 256-row slices ----------
__global__ __launch_bounds__(256) void kv_outer(const u16* __restrict__ kvb,
                                                float* __restrict__ gpart,
                                                float* __restrict__ ksump,
                                                float* __restrict__ vsump) {
    const int bh = blockIdx.x >> 5, s = blockIdx.x & 31;
    const int b = bh >> 3, h = bh & 7;
    const int t = threadIdx.x;
    const int tx = t & 15, ty = t >> 4;
    __shared__ u16 ks[64 * 64];
    __shared__ u16 vs[64 * 64];
    const u16* kg = kvb + ((size_t)(b * 8192 + s * 256)) * 1024 + h * 64;
    const u16* vg = kg + 512;
    const int sr = t >> 3, sc = (t & 7) * 8;

    float acc[4][4];
    for (int i = 0; i < 4; ++i)
        for (int j = 0; j < 4; ++j) acc[i][j] = 0.f;
    float ka[4] = {0.f, 0.f, 0.f, 0.f}, va[4] = {0.f, 0.f, 0.f, 0.f};

    for (int c = 0; c < 4; ++c) {
        const u16* kgc = kg + (size_t)(c * 64 + sr) * 1024 + sc;
        const u16* vgc = vg + (size_t)(c * 64 + sr) * 1024 + sc;
        int4 k0v = *(const int4*)kgc;
        int4 k1v = *(const int4*)(kgc + (size_t)32 * 1024);
        int4 v0v = *(const int4*)vgc;
        int4 v1v = *(const int4*)(vgc + (size_t)32 * 1024);
        __syncthreads();
        *(int4*)(ks + sr * 64 + sc) = k0v;
        *(int4*)(ks + (sr + 32) * 64 + sc) = k1v;
        *(int4*)(vs + sr * 64 + sc) = v0v;
        *(int4*)(vs + (sr + 32) * 64 + sc) = v1v;
        __syncthreads();
#pragma unroll 4
        for (int n = 0; n < 64; ++n) {
            ushort4v k4 = *(const ushort4v*)(ks + n * 64 + ty * 4);
            ushort4v v4 = *(const ushort4v*)(vs + n * 64 + tx * 4);
            float kf[4], vf[4];
#pragma unroll
            for (int i = 0; i < 4; ++i) { kf[i] = bf2f(k4[i]); vf[i] = bf2f(v4[i]); }
#pragma unroll
            for (int i = 0; i < 4; ++i)
#pragma unroll
                for (int j = 0; j < 4; ++j) acc[i][j] += kf[i] * vf[j];
#pragma unroll
            for (int i = 0; i < 4; ++i) { ka[i] += kf[i]; va[i] += vf[i]; }
        }
    }
    size_t gb = ((size_t)(bh * 32 + s)) * 4096;
#pragma unroll
    for (int i = 0; i < 4; ++i)
#pragma unroll
        for (int j = 0; j < 4; ++j)
            gpart[gb + (ty * 4 + i) * 64 + tx * 4 + j] = acc[i][j];
    if (tx == 0)
        for (int i = 0; i < 4; ++i) ksump[(bh * 32 + s) * 64 + ty * 4 + i] = ka[i];
    if (ty == 0)
        for (int i = 0; i < 4; ++i) vsump[(bh * 32 + s) * 64 + tx * 4 + i] = va[i];
}

// ---------- K2b: reduce partials + centering correction, write g fp32 [bh][64][64] ----------
__global__ __launch_bounds__(256) void g_final(const float* __restrict__ gpart,
                                               const float* __restrict__ ksump,
                                               const float* __restrict__ vsump,
                                               float* __restrict__ gfull) {
    const int bh = blockIdx.x >> 4, part = blockIdx.x & 15;
    const int t = threadIdx.x;
    __shared__ float kls[64], vls[64];
    if (t < 64) {
        float s = 0.f;
        for (int j = 0; j < 32; ++j) s += ksump[(bh * 32 + j) * 64 + t];
        kls[t] = s;
    } else if (t < 128) {
        int d = t - 64;
        float s = 0.f;
        for (int j = 0; j < 32; ++j) s += vsump[(bh * 32 + j) * 64 + d];
        vls[d] = s;
    }
    __syncthreads();
    const int idx = part * 256 + t;
    const int d1 = idx >> 6, d2 = idx & 63;
    float s = 0.f;
    for (int j = 0; j < 32; ++j) s += gpart[((size_t)(bh * 32 + j)) * 4096 + idx];
    s -= kls[d1] * vls[d2] * (1.0f / 8192.0f);
    gfull[bh * 4096 + idx] = s;
}

// ---------- K2c: Wg[b][he][c] = sum_d Wq[h*64+d][c] * g[bh][d][e]  (bf16, K-major) ----------
__global__ __launch_bounds__(256) void fold(const float* __restrict__ gfull,
                                            const float* __restrict__ W,
                                            u16* __restrict__ Wgb) {
    const int bh = blockIdx.x >> 3, cb = blockIdx.x & 7;
    const int b = bh >> 3, h = bh & 7;
    const int t = threadIdx.x;
    __shared__ float gs[4096];
    for (int i = t; i < 4096; i += 256) gs[i] = gfull[bh * 4096 + i];
    __syncthreads();
    const int c = cb * 64 + (t & 63);
    const int eg = (t >> 6) * 16;
    float acc[16];
#pragma unroll
    for (int j = 0; j < 16; ++j) acc[j] = 0.f;
    for (int d = 0; d < 64; ++d) {
        float w = W[(size_t)(h * 64 + d) * 512 + c];
#pragma unroll
        for (int j = 0; j < 16; ++j) acc[j] += w * gs[d * 64 + eg + j];
    }
#pragma unroll
    for (int j = 0; j < 16; ++j)
        Wgb[(size_t)(b * 512 + h * 64 + eg + j) * 512 + c] = f2bf(acc[j]);
}

// ---------- K3: z = scale/1024 + (x @ Wg)/1024 ----------
__global__ __launch_bounds__(256) void out_z(const u16* __restrict__ xb,
                                             const u16* __restrict__ Wgb,
                                             float* __restrict__ z) {
    __shared__ u16 As[128 * 32];
    __shared__ u16 Bs[128 * 32];
    const int t = threadIdx.x;
    const int m0 = blockIdx.x * 128;       // global row in [0,16384)
    const int b = blockIdx.x >> 6;         // batch
    const int n0 = blockIdx.y * 128;       // he column block within batch

    f32x4 zz = {0.f, 0.f, 0.f, 0.f};
    f32x4 acc[4][4];
    for (int i = 0; i < 4; ++i)
        for (int j = 0; j < 4; ++j) acc[i][j] = zz;

    gemm_core(xb + (size_t)m0 * 512,
              Wgb + (size_t)b * 262144 + (size_t)n0 * 512, As, Bs, t, acc);

    const int l = t & 63, wv = t >> 6;
    const int lr = l & 15;
    const int wm = (wv >> 1) * 64, wn = (wv & 1) * 64;
#pragma unroll
    for (int mi = 0; mi < 4; ++mi)
#pragma unroll
        for (int ni = 0; ni < 4; ++ni) {
            int he = n0 + wn + ni * 16 + lr;
            int h = he >> 6, e = he & 63;
#pragma unroll
            for (int j = 0; j < 4; ++j) {
                int row = m0 + wm + mi * 16 + (l >> 4) * 4 + j;
                int nidx = row & 8191;
                z[((size_t)(b * 8 + h) * 8192 + nidx) * 64 + e] =
                    (acc[mi][ni][j] + 0.125f) * 0.0009765625f;
            }
        }
}

extern "C" void kernel_launch(void* const* d_in, const int* in_sizes, int n_in,
                              void* d_out, int out_size, void* d_ws, size_t ws_size,
                              hipStream_t stream) {
    const float* x = (const float*)d_in[0];   // [2,8192,512] fp32
    const float* W = (const float*)d_in[1];   // [1536,512] fp32
    float* z = (float*)d_out;                 // [2,8,8192,64] fp32

    char* ws = (char*)d_ws;
    u16* xb      = (u16*)(ws);                  // 16,777,216 B
    u16* wb      = (u16*)(ws + 16777216);       //  1,048,576 B (W_kv rows, bf16)
    u16* kvb     = (u16*)(ws + 17825792);       // 33,554,432 B
    float* gpart = (float*)(ws + 51380224);     //  8,388,608 B
    float* ksump = (float*)(ws + 59768832);     //    131,072 B
    float* vsump = (float*)(ws + 59899904);     //    131,072 B
    float* gfull = (float*)(ws + 60030976);     //    262,144 B
    u16* Wgb     = (u16*)(ws + 60293120);       //  1,048,576 B

    cvt_bf16<<<2048, 256, 0, stream>>>(x, xb, 8388608 / 4);
    cvt_bf16<<<512, 256, 0, stream>>>(W + 262144, wb, 524288 / 4);  // rows 512..1535
    gemm_kv<<<dim3(128, 8), 256, 0, stream>>>(xb, wb, kvb);
    kv_outer<<<512, 256, 0, stream>>>(kvb, gpart, ksump, vsump);
    g_final<<<256, 256, 0, stream>>>(gpart, ksump, vsump, gfull);
    fold<<<128, 256, 0, stream>>>(gfull, W, Wgb);
    out_z<<<dim3(128, 4), 256, 0, stream>>>(xb, Wgb, z);
}